// Round 13
// baseline (103.911 us; speedup 1.0000x reference)
//
#include <hip/hip_runtime.h>

#define IMG_H 512
#define IMG_W 512
#define N_IMG 32
#define ROWS  8                    // output rows per wave-band
#define BANDS (IMG_H / ROWS)       // 64 bands per image
#define NPIX  (32.0f * 512.0f * 512.0f)

// ---- DPP lane shifts (verified R3-R12): wave_shr:1 / wave_shl:1 with
//      bound_ctrl zero-fill = free image-edge zero padding.
__device__ __forceinline__ float dl(float x) {   // lane i <- lane i-1, lane0 <- 0
    return __int_as_float(__builtin_amdgcn_update_dpp(
        0, __float_as_int(x), 0x138, 0xf, 0xf, true));
}
__device__ __forceinline__ float dr(float x) {   // lane i <- lane i+1, lane63 <- 0
    return __int_as_float(__builtin_amdgcn_update_dpp(
        0, __float_as_int(x), 0x130, 0xf, 0xf, true));
}

// Branchless clamped load (single instantiation for ALL bands -- halves code
// vs the two-template split; clamp+select are exact no-ops for in-range rows).
// Out-of-range: I=0, t_raw=-1 so fmaf(-1,0.5,0.5)=0 reproduces zero padding.
// (Semantics verified R5/R7/R11/R12.)
__device__ __forceinline__ void load8c(const float* __restrict__ ip,
                                       const float* __restrict__ tp,
                                       int r, int c0, float* I, float* T) {
    const int rc = min(max(r, 0), IMG_H - 1);
    const float* irow = ip + (ptrdiff_t)rc * IMG_W + c0;
    const float* trow = tp + (ptrdiff_t)rc * IMG_W + c0;
    float4 a = *(const float4*)(irow);
    float4 b = *(const float4*)(irow + 4);
    float4 c = *(const float4*)(trow);
    float4 d = *(const float4*)(trow + 4);
    I[0]=a.x; I[1]=a.y; I[2]=a.z; I[3]=a.w;
    I[4]=b.x; I[5]=b.y; I[6]=b.z; I[7]=b.w;
    T[0]=c.x; T[1]=c.y; T[2]=c.z; T[3]=c.w;
    T[4]=d.x; T[5]=d.y; T[6]=d.z; T[7]=d.w;
    const bool v = (r >= 0) && (r < IMG_H);   // wave-uniform
    #pragma unroll
    for (int j = 0; j < 8; ++j) {
        I[j] = v ? I[j] : 0.0f;
        T[j] = v ? T[j] : -1.0f;
    }
}

// Vertical slides; T normalized at consume site (verified R4/R7/R10/R12).
__device__ __forceinline__ void slide_lead(const float* LI, const float* LTr,
                                           float* vI, float* vT, float* vII,
                                           float* vTT, float* vIT) {
    #pragma unroll
    for (int j = 0; j < 8; ++j) {
        float li = LI[j];
        float lt = fmaf(LTr[j], 0.5f, 0.5f);
        vI[j]  += li;
        vT[j]  += lt;
        vII[j]  = fmaf(li, li, vII[j]);
        vTT[j]  = fmaf(lt, lt, vTT[j]);
        vIT[j]  = fmaf(li, lt, vIT[j]);
    }
}

__device__ __forceinline__ void slide_full(const float* LI, const float* LTr,
                                           const float* QI, const float* QTr,
                                           float* vI, float* vT, float* vII,
                                           float* vTT, float* vIT) {
    #pragma unroll
    for (int j = 0; j < 8; ++j) {
        float li = LI[j], qi = QI[j];
        float lt = fmaf(LTr[j], 0.5f, 0.5f);
        float qt = fmaf(QTr[j], 0.5f, 0.5f);
        float dI = li - qi, aI = li + qi;
        float dT = lt - qt, aT = lt + qt;
        vI[j]  += dI;
        vT[j]  += dT;
        vII[j]  = fmaf(dI, aI, vII[j]);
        vTT[j]  = fmaf(dT, aT, vTT[j]);
        vIT[j]  = fmaf(li, lt, vIT[j] - qi * qt);
    }
}

__device__ __forceinline__ float cc_of(float sI, float sT, float sII, float sTT, float sIT) {
    const float inv81 = 1.0f / 81.0f;
    float u     = sI * inv81;
    float w     = sT * inv81;
    float cross = fmaf(-u, sT, sIT);
    float iv    = fmaf(-u, sI, sII);
    float tv    = fmaf(-w, sT, sTT);
    float den   = fmaf(tv, iv, 1e-5f);
    return cross * cross * __builtin_amdgcn_rcpf(den);
}

// Horizontal 9-tap sums + cc; inline DPP halos (verified R6-R12).
__device__ __forceinline__ float hphase(const float* vI, const float* vT,
                                        const float* vII, const float* vTT,
                                        const float* vIT) {
    float s0 = ((dl(vI [4])+dl(vI [5]))+(dl(vI [6])+dl(vI [7]))) + ((vI [0]+vI [1])+(vI [2]+vI [3])) + vI [4];
    float s1 = ((dl(vT [4])+dl(vT [5]))+(dl(vT [6])+dl(vT [7]))) + ((vT [0]+vT [1])+(vT [2]+vT [3])) + vT [4];
    float s2 = ((dl(vII[4])+dl(vII[5]))+(dl(vII[6])+dl(vII[7]))) + ((vII[0]+vII[1])+(vII[2]+vII[3])) + vII[4];
    float s3 = ((dl(vTT[4])+dl(vTT[5]))+(dl(vTT[6])+dl(vTT[7]))) + ((vTT[0]+vTT[1])+(vTT[2]+vTT[3])) + vTT[4];
    float s4 = ((dl(vIT[4])+dl(vIT[5]))+(dl(vIT[6])+dl(vIT[7]))) + ((vIT[0]+vIT[1])+(vIT[2]+vIT[3])) + vIT[4];
    float part = cc_of(s0, s1, s2, s3, s4);

    #define HSTEP(e0,e1,e2,e3,e4) \
        s0 += (e0); s1 += (e1); s2 += (e2); s3 += (e3); s4 += (e4); \
        part += cc_of(s0, s1, s2, s3, s4);

    HSTEP(vI[5]-dl(vI[4]), vT[5]-dl(vT[4]), vII[5]-dl(vII[4]), vTT[5]-dl(vTT[4]), vIT[5]-dl(vIT[4]))     // j=1
    HSTEP(vI[6]-dl(vI[5]), vT[6]-dl(vT[5]), vII[6]-dl(vII[5]), vTT[6]-dl(vTT[5]), vIT[6]-dl(vIT[5]))     // j=2
    HSTEP(vI[7]-dl(vI[6]), vT[7]-dl(vT[6]), vII[7]-dl(vII[6]), vTT[7]-dl(vTT[6]), vIT[7]-dl(vIT[6]))     // j=3
    HSTEP(dr(vI[0])-dl(vI[7]), dr(vT[0])-dl(vT[7]), dr(vII[0])-dl(vII[7]),
          dr(vTT[0])-dl(vTT[7]), dr(vIT[0])-dl(vIT[7]))                                                  // j=4
    HSTEP(dr(vI[1])-vI[0], dr(vT[1])-vT[0], dr(vII[1])-vII[0], dr(vTT[1])-vTT[0], dr(vIT[1])-vIT[0])     // j=5
    HSTEP(dr(vI[2])-vI[1], dr(vT[2])-vT[1], dr(vII[2])-vII[1], dr(vTT[2])-vTT[1], dr(vIT[2])-vIT[1])     // j=6
    HSTEP(dr(vI[3])-vI[2], dr(vT[3])-vT[2], dr(vII[3])-vII[2], dr(vTT[3])-vTT[2], dr(vIT[3])-vIT[2])     // j=7
    #undef HSTEP
    return part;
}

// Band body: trail rows kept IN REGISTERS (7 slots S0..S6) -- hot loop has
// NO trail loads; each freed trail slot is reused as the next lead buffer.
// 16 row-loads/band instead of 23 (-30% memory requests).
// Iter m=0..15: lead row r0+m-4; trail row r0+m-13 = slot S[m-9] (m>=9);
// hphase on m=8..15 -> output rows r0..r0+7.
__device__ __forceinline__ float band_body(const float* __restrict__ ip,
                                           const float* __restrict__ tp,
                                           int r0, int c0) {
    float vI[8] = {}, vT[8] = {}, vII[8] = {}, vTT[8] = {}, vIT[8] = {};
    float acc = 0.0f;

    float S0I[8],S0T[8], S1I[8],S1T[8], S2I[8],S2T[8], S3I[8],S3T[8];
    float S4I[8],S4T[8], S5I[8],S5T[8], S6I[8],S6T[8];
    float XAI[8],XAT[8], XBI[8],XBT[8], XCI[8],XCT[8];

    // ---- prologue: issue all 10 row loads (rows r0-4 .. r0+5) ----
    load8c(ip, tp, r0 - 4, c0, S0I, S0T);    // trail slot rows r0-4..r0+2
    load8c(ip, tp, r0 - 3, c0, S1I, S1T);
    load8c(ip, tp, r0 - 2, c0, S2I, S2T);
    load8c(ip, tp, r0 - 1, c0, S3I, S3T);
    load8c(ip, tp, r0 + 0, c0, S4I, S4T);
    load8c(ip, tp, r0 + 1, c0, S5I, S5T);
    load8c(ip, tp, r0 + 2, c0, S6I, S6T);
    load8c(ip, tp, r0 + 3, c0, XAI, XAT);    // ramp-only rows
    load8c(ip, tp, r0 + 4, c0, XBI, XBT);
    load8c(ip, tp, r0 + 5, c0, XCI, XCT);    // lead(9)

    // ---- ramp: iters 0..7 (rows r0-4 .. r0+3) ----
    slide_lead(S0I, S0T, vI, vT, vII, vTT, vIT);
    slide_lead(S1I, S1T, vI, vT, vII, vTT, vIT);
    slide_lead(S2I, S2T, vI, vT, vII, vTT, vIT);
    slide_lead(S3I, S3T, vI, vT, vII, vTT, vIT);
    slide_lead(S4I, S4T, vI, vT, vII, vTT, vIT);
    slide_lead(S5I, S5T, vI, vT, vII, vTT, vIT);
    slide_lead(S6I, S6T, vI, vT, vII, vTT, vIT);
    slide_lead(XAI, XAT, vI, vT, vII, vTT, vIT);

    // ---- iter 8: window full (rows r0-4..r0+4) -> output r0 ----
    slide_lead(XBI, XBT, vI, vT, vII, vTT, vIT);
    acc += hphase(vI, vT, vII, vTT, vIT);

    // ---- hot: iters 9..15; trail from register slot, slot reused for the
    //      next lead (loaded 1 iteration ahead of consumption) ----
    slide_full(XCI, XCT, S0I, S0T, vI, vT, vII, vTT, vIT);   // m= 9: +r0+5 -r0-4
    load8c(ip, tp, r0 + 6, c0, S0I, S0T);                    //       lead(10)
    acc += hphase(vI, vT, vII, vTT, vIT);                    // -> r0+1

    slide_full(S0I, S0T, S1I, S1T, vI, vT, vII, vTT, vIT);   // m=10: +r0+6 -r0-3
    load8c(ip, tp, r0 + 7, c0, S1I, S1T);                    //       lead(11)
    acc += hphase(vI, vT, vII, vTT, vIT);                    // -> r0+2

    slide_full(S1I, S1T, S2I, S2T, vI, vT, vII, vTT, vIT);   // m=11: +r0+7 -r0-2
    load8c(ip, tp, r0 + 8, c0, S2I, S2T);                    //       lead(12)
    acc += hphase(vI, vT, vII, vTT, vIT);                    // -> r0+3

    slide_full(S2I, S2T, S3I, S3T, vI, vT, vII, vTT, vIT);   // m=12: +r0+8 -r0-1
    load8c(ip, tp, r0 + 9, c0, S3I, S3T);                    //       lead(13)
    acc += hphase(vI, vT, vII, vTT, vIT);                    // -> r0+4

    slide_full(S3I, S3T, S4I, S4T, vI, vT, vII, vTT, vIT);   // m=13: +r0+9 -r0+0
    load8c(ip, tp, r0 + 10, c0, S4I, S4T);                   //       lead(14)
    acc += hphase(vI, vT, vII, vTT, vIT);                    // -> r0+5

    slide_full(S4I, S4T, S5I, S5T, vI, vT, vII, vTT, vIT);   // m=14: +r0+10 -r0+1
    load8c(ip, tp, r0 + 11, c0, S5I, S5T);                   //       lead(15)
    acc += hphase(vI, vT, vII, vTT, vIT);                    // -> r0+6

    slide_full(S5I, S5T, S6I, S6T, vI, vT, vII, vTT, vIT);   // m=15: +r0+11 -r0+2
    acc += hphase(vI, vT, vII, vTT, vIT);                    // -> r0+7

    return acc;
}

__global__ __launch_bounds__(256)      // no min-occupancy coercion (R6 lesson);
void cc_loss_kernel(const float* __restrict__ in, const float* __restrict__ tg,
                    float* __restrict__ out) {
    // grid-limited to 2 waves/SIMD -> ~215 VGPR is free; spend on trail slots.
    __shared__ float red[4];

    const int t    = threadIdx.x;
    const int w    = t >> 6;
    const int lane = t & 63;

    // XCD-chunked swizzle (verified R4/R10/R12).
    const int bid  = blockIdx.x;                       // 0..511
    const int bs   = (bid & 7) * 64 + (bid >> 3);      // bijective (512 % 8 == 0)

    const int gband = bs * 4 + w;              // 0..2047
    const int b     = gband >> 6;              // image (64 bands each)
    const int band  = gband & 63;
    const int r0    = band * ROWS;
    const size_t base = (size_t)b * (IMG_H * IMG_W);
    const float* ip = in + base;
    const float* tp = tg + base;
    const int c0    = lane * 8;                // own image cols c0..c0+7

    float acc = band_body(ip, tp, r0, c0);     // single body, all bands

    // ---- reduction: wave shuffle, one barrier per block, one atomic ----
    #pragma unroll
    for (int off = 32; off > 0; off >>= 1) acc += __shfl_down(acc, off, 64);
    if (lane == 0) red[w] = acc;
    __syncthreads();
    if (t == 0)
        atomicAdd(out, (red[0] + red[1] + red[2] + red[3]) * (-1.0f / NPIX));
}

extern "C" void kernel_launch(void* const* d_in, const int* in_sizes, int n_in,
                              void* d_out, int out_size, void* d_ws, size_t ws_size,
                              hipStream_t stream) {
    const float* in = (const float*)d_in[0];
    const float* tg = (const float*)d_in[1];
    float* out = (float*)d_out;

    hipMemsetAsync(out, 0, sizeof(float), stream);
    dim3 grid(N_IMG * BANDS / 4);              // 512 blocks x 4 wave-bands
    cc_loss_kernel<<<grid, 256, 0, stream>>>(in, tg, out);
}